// Round 13
// baseline (211.837 us; speedup 1.0000x reference)
//
#include <hip/hip_runtime.h>
#include <stdint.h>

// ---------------- types ----------------
typedef short bf16x8 __attribute__((ext_vector_type(8)));
typedef float f32x4  __attribute__((ext_vector_type(4)));

__device__ __forceinline__ uint16_t f2bf(float f) {
    uint32_t u = __float_as_uint(f);
    u += 0x7FFF + ((u >> 16) & 1);   // round-to-nearest-even
    return (uint16_t)(u >> 16);
}
__device__ __forceinline__ uint32_t pk2bf(float a, float b) {
    return (uint32_t)f2bf(a) | ((uint32_t)f2bf(b) << 16);
}

typedef __attribute__((address_space(1))) const uint32_t gu32;
typedef __attribute__((address_space(3))) uint32_t lu32;
__device__ __forceinline__ void gload16(const void* g, void* l) {
    // async global->LDS, 16B/lane; LDS dest = wave-uniform base + lane*16 (m104/m108)
    __builtin_amdgcn_global_load_lds((gu32*)g, (lu32*)l, 16, 0, 0);
}

// =====================================================================
// prep: ALL prologue work in ONE kernel (was 4 launches).
//   blocks [0,4096):        X fp32 -> bf16 (flat, float4)
//   blocks [4096,5120):     W1 transpose  (R=256,C=512, 8e, 16x8 tiles)
//   blocks [5120,7168):     W2 transpose  (R=512,C=512, 8e, 16x16 tiles)
//   blocks [7168,7296):     W3 transpose  (R=512,C=32,  8e, 1x16 tiles)
// Bodies identical to the round-1..12 verified transpose/cvt kernels.
// =====================================================================
__global__ __launch_bounds__(256) void prep(
    const float* __restrict__ X,  const float* __restrict__ W1,
    const float* __restrict__ W2, const float* __restrict__ W3,
    uint16_t* __restrict__ xbf, uint16_t* __restrict__ w1t,
    uint16_t* __restrict__ w2t, uint16_t* __restrict__ w3t)
{
    const int b = blockIdx.x, tid = threadIdx.x;
    if (b < 4096) {                       // ---- cvt X ----
        const int i = b * 256 + tid;      // 4096*256 == 16384*256/4 exactly
        const float4 v = ((const float4*)X)[i];
        ushort4 h;
        h.x = f2bf(v.x); h.y = f2bf(v.y); h.z = f2bf(v.z); h.w = f2bf(v.w);
        ((ushort4*)xbf)[i] = h;
        return;
    }
    // ---- transposes (block-uniform branch; safe with __syncthreads) ----
    __shared__ float t[32][33];
    const int tx = tid & 31, ty = tid >> 5;
    const float* in; uint16_t* out; int R, C, bx, by, e;
    if (b < 5120) {        // W1
        const int bb = b - 4096; e = bb >> 7; const int rem = bb & 127;
        bx = rem & 15; by = rem >> 4; R = 256; C = 512; in = W1; out = w1t;
    } else if (b < 7168) { // W2
        const int bb = b - 5120; e = bb >> 8; const int rem = bb & 255;
        bx = rem & 15; by = rem >> 4; R = 512; C = 512; in = W2; out = w2t;
    } else {               // W3
        const int bb = b - 7168; e = bb >> 4; bx = 0; by = bb & 15;
        R = 512; C = 32; in = W3; out = w3t;
    }
    const int r0 = by * 32, c0 = bx * 32;
    const float* ine = in + (size_t)e * R * C;
    uint16_t* oute   = out + (size_t)e * R * C;
#pragma unroll
    for (int j = 0; j < 4; ++j)
        t[ty + 8 * j][tx] = ine[(size_t)(r0 + ty + 8 * j) * C + (c0 + tx)];
    __syncthreads();
#pragma unroll
    for (int j = 0; j < 4; ++j) {
        const int orow = c0 + ty + 8 * j;
        const int ocol = r0 + tx;
        oute[(size_t)orow * R + ocol] = f2bf(t[tx][ty + 8 * j]);
    }
}

// =====================================================================
// Layer 1: 256x256 tile, BK=64, 8 waves, r12-verified 2-phase schedule
// (STAGE before compute; __syncthreads = the one race-free gate/tile).
// Both-sides 16B-slot XOR swizzle (r7-verified: conflicts == 0).
// Swapped MFMA: D = mfma(A=W frag [n][k], B=act frag [m][k])
//   -> D col(lane&15)=batch row, row(kg*4+v)=out col.
// =====================================================================
template <int K>
__global__ __launch_bounds__(512, 1) void gemm256(
    const uint16_t* __restrict__ Act,   // activations, + e*actEStride, [Mc][K]
    size_t actEStride,                  // 0 when shared across e (layer 1)
    const uint16_t* __restrict__ Wt,    // [8][512][K] bf16 (n-major, k-contig)
    const float* __restrict__ bias,     // [8][512]
    uint16_t* __restrict__ Out,         // + e*outEStride, [Mc][512] bf16 (relu'd)
    size_t outEStride)
{
    extern __shared__ char smem[];      // 2 x 64KB: [W 32K | Act 32K]
    const int tid = threadIdx.x, wid = tid >> 6, lane = tid & 63;
    const int kg = lane >> 4, lr = lane & 15;
    const int e   = blockIdx.x;
    const int nb0 = blockIdx.y * 256;
    const int m0  = blockIdx.z * 256;
    const int wm = wid >> 2, wn = wid & 3;

    const uint16_t* Wbase = Wt  + ((size_t)e * 512 + nb0) * K;
    const uint16_t* Abase = Act + (size_t)e * actEStride + (size_t)m0 * K;
    uint16_t* Obase       = Out + (size_t)e * outEStride;

    f32x4 acc[8][4];
#pragma unroll
    for (int b = 0; b < 8; ++b)
#pragma unroll
        for (int c = 0; c < 4; ++c) acc[b][c] = f32x4{0.f, 0.f, 0.f, 0.f};

    const int rlo = lane >> 3, pslot = lane & 7;   // staging lane map
    const int lswz = (pslot ^ rlo) * 8;            // pre-swizzled source k-offset

    auto STAGE = [&](int p, int ks) {
#pragma unroll
        for (int g = 0; g < 4; ++g) {
            const int row = g * 64 + wid * 8 + rlo;    // row&7 == rlo
            gload16(Wbase + (size_t)row * K + ks + lswz,
                    smem + p * 65536 + g * 8192 + wid * 1024);
        }
#pragma unroll
        for (int g = 0; g < 4; ++g) {
            const int row = g * 64 + wid * 8 + rlo;
            gload16(Abase + (size_t)row * K + ks + lswz,
                    smem + p * 65536 + 32768 + g * 8192 + wid * 1024);
        }
    };

    constexpr int NT = K / 64;
    STAGE(0, 0);
    __syncthreads();

#pragma unroll
    for (int t = 0; t < NT; ++t) {
        const int cur = t & 1;
        if (t + 1 < NT)
            STAGE(1 - cur, (t + 1) * 64);        // prefetch BEFORE compute
        asm volatile("" ::: "memory");

        const char* sW = smem + cur * 65536;
        const char* sA = sW + 32768;
        __builtin_amdgcn_s_setprio(1);
#pragma unroll
        for (int kh = 0; kh < 2; ++kh) {
            bf16x8 wf[4], af[8];
#pragma unroll
            for (int c = 0; c < 4; ++c) {
                const int row = wn * 64 + c * 16 + lr;
                wf[c] = *(const bf16x8*)(sW + row * 128 +
                                         (((kh * 4 + kg) ^ (row & 7)) << 4));
            }
#pragma unroll
            for (int b = 0; b < 8; ++b) {
                const int row = wm * 128 + b * 16 + lr;
                af[b] = *(const bf16x8*)(sA + row * 128 +
                                         (((kh * 4 + kg) ^ (row & 7)) << 4));
            }
#pragma unroll
            for (int b = 0; b < 8; ++b)
#pragma unroll
                for (int c = 0; c < 4; ++c)
                    acc[b][c] = __builtin_amdgcn_mfma_f32_16x16x32_bf16(wf[c], af[b], acc[b][c], 0, 0, 0);
        }
        __builtin_amdgcn_s_setprio(0);
        __syncthreads();
    }

    // epilogue: bias + relu -> bf16, 8B stores, row-contiguous
#pragma unroll
    for (int c = 0; c < 4; ++c) {
        const int col = nb0 + wn * 64 + c * 16 + kg * 4;
        const float4 bv = *(const float4*)(bias + e * 512 + col);
#pragma unroll
        for (int b = 0; b < 8; ++b) {
            const float x0 = fmaxf(acc[b][c][0] + bv.x, 0.f);
            const float x1 = fmaxf(acc[b][c][1] + bv.y, 0.f);
            const float x2 = fmaxf(acc[b][c][2] + bv.z, 0.f);
            const float x3 = fmaxf(acc[b][c][3] + bv.w, 0.f);
            uint2 w;
            w.x = pk2bf(x0, x1);
            w.y = pk2bf(x2, x3);
            const int row = m0 + wm * 128 + b * 16 + lr;
            *(uint2*)(Obase + (size_t)row * 512 + col) = w;
        }
    }
}

// =====================================================================
// Fused layers 2+3 (r10-verified dataflow + r12-verified schedule).
// Per block: 256 batch rows x one e -> out[256][32]. Two n-half passes:
// each = 2-phase K-loop over W2[half*256..+256) (h2 never leaves LDS),
// then h2half (bias+relu bf16) into the drained 128KB LDS (swizzled),
// barrier, L3 partial-accumulate out += h2half @ W3[:, khalf] with W3
// frags from global (32KB/e, XCD-L2-resident). Saves h2's 268MB of
// L2/L3 traffic vs the split pipeline; h1 read ONCE (BN=512 internal).
// =====================================================================
__global__ __launch_bounds__(512, 1) void gemm_l23(
    const uint16_t* __restrict__ H1,    // + e*h1EStride, [Mc][512]
    size_t h1EStride,
    const uint16_t* __restrict__ W2t,   // [8][512][512] bf16 (n-major, k-contig)
    const float* __restrict__ b2,       // [8][512]
    const uint16_t* __restrict__ W3t,   // [8][32][512]  bf16 (o-major, k-contig)
    const float* __restrict__ b3,       // [8][32]
    float* __restrict__ Out)            // chunk base of [B][256] fp32
{
    extern __shared__ char smem[];      // 128KB staging / h2half[256][256] bf16
    const int tid = threadIdx.x, wid = tid >> 6, lane = tid & 63;
    const int kg = lane >> 4, lr = lane & 15;
    const int e  = blockIdx.x;
    const int m0 = blockIdx.z * 256;
    const int wm = wid >> 2, wn = wid & 3;

    const uint16_t* Abase = H1 + (size_t)e * h1EStride + (size_t)m0 * 512;
    const uint16_t* W3e   = W3t + (size_t)e * 32 * 512;

    const int rlo = lane >> 3, pslot = lane & 7;
    const int lswz = (pslot ^ rlo) * 8;

    f32x4 oacc[2][2];                    // out acc [m-frag][o-frag], persists
#pragma unroll
    for (int i = 0; i < 2; ++i)
#pragma unroll
        for (int j = 0; j < 2; ++j) oacc[i][j] = f32x4{0.f, 0.f, 0.f, 0.f};

    for (int half = 0; half < 2; ++half) {
        const uint16_t* Wbase = W2t + ((size_t)e * 512 + half * 256) * 512;

        f32x4 acc[8][4];
#pragma unroll
        for (int b = 0; b < 8; ++b)
#pragma unroll
            for (int c = 0; c < 4; ++c) acc[b][c] = f32x4{0.f, 0.f, 0.f, 0.f};

        auto STAGE = [&](int p, int ks) {
#pragma unroll
            for (int g = 0; g < 4; ++g) {
                const int row = g * 64 + wid * 8 + rlo;
                gload16(Wbase + (size_t)row * 512 + ks + lswz,
                        smem + p * 65536 + g * 8192 + wid * 1024);
            }
#pragma unroll
            for (int g = 0; g < 4; ++g) {
                const int row = g * 64 + wid * 8 + rlo;
                gload16(Abase + (size_t)row * 512 + ks + lswz,
                        smem + p * 65536 + 32768 + g * 8192 + wid * 1024);
            }
        };

        STAGE(0, 0);
        __syncthreads();
#pragma unroll
        for (int t = 0; t < 8; ++t) {
            const int cur = t & 1;
            if (t + 1 < 8)
                STAGE(1 - cur, (t + 1) * 64);    // prefetch BEFORE compute
            asm volatile("" ::: "memory");

            const char* sW = smem + cur * 65536;
            const char* sA = sW + 32768;
            __builtin_amdgcn_s_setprio(1);
#pragma unroll
            for (int kh = 0; kh < 2; ++kh) {
                bf16x8 wf[4], af[8];
#pragma unroll
                for (int c = 0; c < 4; ++c) {
                    const int row = wn * 64 + c * 16 + lr;
                    wf[c] = *(const bf16x8*)(sW + row * 128 +
                                             (((kh * 4 + kg) ^ (row & 7)) << 4));
                }
#pragma unroll
                for (int b = 0; b < 8; ++b) {
                    const int row = wm * 128 + b * 16 + lr;
                    af[b] = *(const bf16x8*)(sA + row * 128 +
                                             (((kh * 4 + kg) ^ (row & 7)) << 4));
                }
#pragma unroll
                for (int b = 0; b < 8; ++b)
#pragma unroll
                    for (int c = 0; c < 4; ++c)
                        acc[b][c] = __builtin_amdgcn_mfma_f32_16x16x32_bf16(wf[c], af[b], acc[b][c], 0, 0, 0);
            }
            __builtin_amdgcn_s_setprio(0);
            __syncthreads();   // drains prefetch + publishes; last iter frees LDS
        }

        // ---- epilogue: bias+relu -> bf16 h2half[256 m][256 k'] swizzled ----
#pragma unroll
        for (int c = 0; c < 4; ++c) {
            const int coll = wn * 64 + c * 16 + kg * 4;   // local n (= L3 k) 0..255
            const float4 bv = *(const float4*)(b2 + e * 512 + half * 256 + coll);
#pragma unroll
            for (int b = 0; b < 8; ++b) {
                const float x0 = fmaxf(acc[b][c][0] + bv.x, 0.f);
                const float x1 = fmaxf(acc[b][c][1] + bv.y, 0.f);
                const float x2 = fmaxf(acc[b][c][2] + bv.z, 0.f);
                const float x3 = fmaxf(acc[b][c][3] + bv.w, 0.f);
                uint2 w;
                w.x = pk2bf(x0, x1);
                w.y = pk2bf(x2, x3);
                const int row = wm * 128 + b * 16 + lr;   // m-row 0..255
                *(uint2*)(smem + row * 512 + ((coll * 2) ^ ((row & 7) << 4))) = w;
            }
        }
        __syncthreads();   // h2half visible to all waves

        // ---- L3 partial: out += h2half @ W3[:, half*256..+256) ----
        // swapped MFMA: D=mfma(A=W3 frag [o][k], B=h2 frag [m][k])
        //   -> col(lane&15)=m-row, row(kg*4+v)=o-col.   (r10-verified)
#pragma unroll
        for (int mf = 0; mf < 2; ++mf)
#pragma unroll
            for (int kc = 0; kc < 8; ++kc) {
                const int row = wid * 32 + mf * 16 + lr;
                const bf16x8 hb = *(const bf16x8*)(smem + row * 512 +
                                                   (((kc * 4 + kg) << 4) ^ ((row & 7) << 4)));
#pragma unroll
                for (int of = 0; of < 2; ++of) {
                    const bf16x8 wf = *(const bf16x8*)(W3e + (size_t)(of * 16 + lr) * 512 +
                                                       half * 256 + kc * 32 + kg * 8);
                    oacc[mf][of] = __builtin_amdgcn_mfma_f32_16x16x32_bf16(wf, hb, oacc[mf][of], 0, 0, 0);
                }
            }
        __syncthreads();   // h2half consumed; safe to re-stage next half
    }

    // ---- final store: bias3 + float4, row-contiguous (r10-verified) ----
#pragma unroll
    for (int mf = 0; mf < 2; ++mf)
#pragma unroll
        for (int of = 0; of < 2; ++of) {
            const int col = e * 32 + of * 16 + kg * 4;
            const float4 bv = *(const float4*)(b3 + col);
            const int row = m0 + wid * 32 + mf * 16 + lr;
            float4 res;
            res.x = oacc[mf][of][0] + bv.x;
            res.y = oacc[mf][of][1] + bv.y;
            res.z = oacc[mf][of][2] + bv.z;
            res.w = oacc[mf][of][3] + bv.w;
            *(float4*)(Out + (size_t)row * 256 + col) = res;
        }
}

// =====================================================================
// Fallback (round-3 fused kernel, 14.25MB ws) — only if ws too small.
// =====================================================================
template <int K, bool B_LDS>
__device__ __forceinline__ void layer128(
    const uint16_t* __restrict__ Aw, const uint16_t* __restrict__ Bg,
    const char* __restrict__ Bl, const float* __restrict__ bias,
    char* __restrict__ ldsOut, int n0, int kg, int lr, bool syncBeforeEpi) {
    f32x4 acc[8][4];
#pragma unroll
    for (int m = 0; m < 8; ++m)
#pragma unroll
        for (int n = 0; n < 4; ++n) acc[m][n] = f32x4{0.f, 0.f, 0.f, 0.f};
    auto ldA = [&](int mf, int k0) -> bf16x8 {
        return *(const bf16x8*)(Aw + (size_t)(mf * 16 + lr) * K + k0 + kg * 8);
    };
    auto ldB = [&](int nf, int k0) -> bf16x8 {
        if constexpr (B_LDS) {
            const int row = nf * 16 + lr;
            return *(const bf16x8*)(Bl + row * 1024 +
                                    ((((k0 + kg * 8) << 1)) ^ ((row & 7) << 4)));
        } else {
            return *(const bf16x8*)(Bg + (size_t)(nf * 16 + lr) * K + k0 + kg * 8);
        }
    };
    bf16x8 a0[8], b0[4], a1[8], b1[4];
#pragma unroll
    for (int i = 0; i < 8; ++i) a0[i] = ldA(i, 0);
#pragma unroll
    for (int i = 0; i < 4; ++i) b0[i] = ldB(i, 0);
#pragma unroll
    for (int k0 = 0; k0 < K; k0 += 64) {
#pragma unroll
        for (int i = 0; i < 8; ++i) a1[i] = ldA(i, k0 + 32);
#pragma unroll
        for (int i = 0; i < 4; ++i) b1[i] = ldB(i, k0 + 32);
#pragma unroll
        for (int m = 0; m < 8; ++m)
#pragma unroll
            for (int n = 0; n < 4; ++n)
                acc[m][n] = __builtin_amdgcn_mfma_f32_16x16x32_bf16(a0[m], b0[n], acc[m][n], 0, 0, 0);
        if (k0 + 64 < K) {
#pragma unroll
            for (int i = 0; i < 8; ++i) a0[i] = ldA(i, k0 + 64);
#pragma unroll
            for (int i = 0; i < 4; ++i) b0[i] = ldB(i, k0 + 64);
        }
#pragma unroll
        for (int m = 0; m < 8; ++m)
#pragma unroll
            for (int n = 0; n < 4; ++n)
                acc[m][n] = __builtin_amdgcn_mfma_f32_16x16x32_bf16(a1[m], b1[n], acc[m][n], 0, 0, 0);
    }
    if (syncBeforeEpi) __syncthreads();
#pragma unroll
    for (int mf = 0; mf < 8; ++mf) {
        const float4 bv = *(const float4*)(bias + mf * 16 + kg * 4);
#pragma unroll
        for (int nf = 0; nf < 4; ++nf) {
            float x0 = fmaxf(acc[mf][nf][0] + bv.x, 0.f);
            float x1 = fmaxf(acc[mf][nf][1] + bv.y, 0.f);
            float x2 = fmaxf(acc[mf][nf][2] + bv.z, 0.f);
            float x3 = fmaxf(acc[mf][nf][3] + bv.w, 0.f);
            uint2 w;
            w.x = pk2bf(x0, x1);
            w.y = pk2bf(x2, x3);
            const int row = nf * 16 + lr;
            const int colbyte = (n0 + mf * 16 + kg * 4) << 1;
            *(uint2*)(ldsOut + row * 1024 + (colbyte ^ ((row & 7) << 4))) = w;
        }
    }
}

__global__ __launch_bounds__(256, 2) void fused_mlp(
    const uint16_t* __restrict__ Xbf,
    const uint16_t* __restrict__ W1T, const float* __restrict__ b1,
    const uint16_t* __restrict__ W2T, const float* __restrict__ b2,
    const uint16_t* __restrict__ W3T, const float* __restrict__ b3,
    float* __restrict__ out) {
    extern __shared__ char hbuf[];
    const int tid = threadIdx.x, wid = tid >> 6, lane = tid & 63;
    const int kg = lane >> 4, lr = lane & 15;
    const int e  = blockIdx.x & 7;
    const int b0 = (blockIdx.x >> 3) * 64;
    const int n0 = wid * 128;
    layer128<256, false>(W1T + ((size_t)e * 512 + n0) * 256, Xbf + (size_t)b0 * 256,
                         nullptr, b1 + e * 512 + n0, hbuf, n0, kg, lr, false);
    __syncthreads();
    layer128<512, true>(W2T + ((size_t)e * 512 + n0) * 512, nullptr, hbuf,
                        b2 + e * 512 + n0, hbuf, n0, kg, lr, true);
    __syncthreads();
    {
        const int rowB  = wid * 16 + lr;
        const int bbyte = rowB * 1024;
        const int bswz  = (rowB & 7) << 4;
        const uint16_t* W3e = W3T + (size_t)e * 32 * 512;
        f32x4 acc[2];
        acc[0] = f32x4{0.f, 0.f, 0.f, 0.f};
        acc[1] = f32x4{0.f, 0.f, 0.f, 0.f};
#pragma unroll
        for (int k0 = 0; k0 < 512; k0 += 32) {
            bf16x8 a = *(const bf16x8*)(hbuf + bbyte + ((((k0 + kg * 8) << 1)) ^ bswz));
#pragma unroll
            for (int nf = 0; nf < 2; ++nf) {
                bf16x8 b = *(const bf16x8*)(W3e + (size_t)(nf * 16 + lr) * 512 + k0 + kg * 8);
                acc[nf] = __builtin_amdgcn_mfma_f32_16x16x32_bf16(a, b, acc[nf], 0, 0, 0);
            }
        }
#pragma unroll
        for (int nf = 0; nf < 2; ++nf) {
            const float bb = b3[e * 32 + nf * 16 + lr];
#pragma unroll
            for (int v = 0; v < 4; ++v) {
                const int row = b0 + wid * 16 + kg * 4 + v;
                out[(size_t)row * 256 + e * 32 + nf * 16 + lr] = acc[nf][v] + bb;
            }
        }
    }
}

// ---------------- host launch ----------------
extern "C" void kernel_launch(void* const* d_in, const int* in_sizes, int n_in,
                              void* d_out, int out_size, void* d_ws, size_t ws_size,
                              hipStream_t stream) {
    (void)in_sizes; (void)n_in; (void)out_size;
    const float* X  = (const float*)d_in[0];   // [16384,256]
    const float* W1 = (const float*)d_in[1];   // [8,256,512]
    const float* b1 = (const float*)d_in[2];   // [8,512]
    const float* W2 = (const float*)d_in[3];   // [8,512,512]
    const float* b2 = (const float*)d_in[4];   // [8,512]
    const float* W3 = (const float*)d_in[5];   // [8,512,32]
    const float* b3 = (const float*)d_in[6];   // [8,32]
    float* out = (float*)d_out;                // [16384,8,32]

    uint16_t* w1t = (uint16_t*)d_ws;           // [8][512][256] bf16  (2 MB)
    uint16_t* w2t = w1t + 8 * 256 * 512;       // [8][512][512] bf16  (4 MB)
    uint16_t* w3t = w2t + 8 * 512 * 512;       // [8][32][512]  bf16  (256 KB)
    uint16_t* xbf = w3t + 8 * 512 * 32;        // [16384][256]  bf16  (8 MB)
    uint16_t* h1  = xbf + (size_t)16384 * 256; // [8][Mc][512] bf16, e-major
    const size_t FIXED_BYTES = ((size_t)(8 * 256 * 512) + 8 * 512 * 512 + 8 * 32 * 512 +
                                (size_t)16384 * 256) * 2;   // 14,942,208

    // largest chunk whose e-indexed h1 fits (h2 eliminated by L2+L3 fusion);
    // Mc=16384 bound == old Mc=8192 bound (proven satisfied in r6-r12).
    int Mc = 0;
    for (int cand = 16384; cand >= 2048; cand >>= 1) {
        if (ws_size >= FIXED_BYTES + (size_t)8192 * cand) { Mc = cand; break; }
    }

    prep<<<7296, 256, 0, stream>>>(X, W1, W2, W3, xbf, w1t, w2t, w3t);

    if (Mc > 0) {
        const size_t eStr = (size_t)Mc * 512;
        (void)hipFuncSetAttribute((const void*)gemm256<256>,
                                  hipFuncAttributeMaxDynamicSharedMemorySize, 131072);
        (void)hipFuncSetAttribute((const void*)gemm_l23,
                                  hipFuncAttributeMaxDynamicSharedMemorySize, 131072);
        for (int c0 = 0; c0 < 16384; c0 += Mc) {
            gemm256<256><<<dim3(8, 2, Mc / 256), 512, 131072, stream>>>(
                xbf + (size_t)c0 * 256, 0, w1t, b1, h1, eStr);
            gemm_l23<<<dim3(8, 1, Mc / 256), 512, 131072, stream>>>(
                h1, eStr, w2t, b2, w3t, b3, out + (size_t)c0 * 256);
        }
    } else {
        (void)hipFuncSetAttribute((const void*)fused_mlp,
                                  hipFuncAttributeMaxDynamicSharedMemorySize, 65536);
        fused_mlp<<<2048, 256, 65536, stream>>>(xbf, w1t, b1, w2t, b2, w3t, b3, out);
    }
}

// Round 14
// 203.433 us; speedup vs baseline: 1.0413x; 1.0413x over previous
//
#include <hip/hip_runtime.h>
#include <stdint.h>

// ---------------- types ----------------
typedef short bf16x8 __attribute__((ext_vector_type(8)));
typedef float f32x4  __attribute__((ext_vector_type(4)));

__device__ __forceinline__ uint16_t f2bf(float f) {
    uint32_t u = __float_as_uint(f);
    u += 0x7FFF + ((u >> 16) & 1);   // round-to-nearest-even
    return (uint16_t)(u >> 16);
}
__device__ __forceinline__ uint32_t pk2bf(float a, float b) {
    return (uint32_t)f2bf(a) | ((uint32_t)f2bf(b) << 16);
}

typedef __attribute__((address_space(1))) const uint32_t gu32;
typedef __attribute__((address_space(3))) uint32_t lu32;
__device__ __forceinline__ void gload16(const void* g, void* l) {
    // async global->LDS, 16B/lane (one call stages 1KB per wave)
    __builtin_amdgcn_global_load_lds((gu32*)g, (lu32*)l, 16, 0, 0);
}

// =====================================================================
// prep: all prologue work in one kernel (r13-verified).
// =====================================================================
__global__ __launch_bounds__(256) void prep(
    const float* __restrict__ X,  const float* __restrict__ W1,
    const float* __restrict__ W2, const float* __restrict__ W3,
    uint16_t* __restrict__ xbf, uint16_t* __restrict__ w1t,
    uint16_t* __restrict__ w2t, uint16_t* __restrict__ w3t)
{
    const int b = blockIdx.x, tid = threadIdx.x;
    if (b < 4096) {                       // cvt X
        const int i = b * 256 + tid;
        const float4 v = ((const float4*)X)[i];
        ushort4 h;
        h.x = f2bf(v.x); h.y = f2bf(v.y); h.z = f2bf(v.z); h.w = f2bf(v.w);
        ((ushort4*)xbf)[i] = h;
        return;
    }
    __shared__ float t[32][33];
    const int tx = tid & 31, ty = tid >> 5;
    const float* in; uint16_t* out; int R, C, bx, by, e;
    if (b < 5120) {
        const int bb = b - 4096; e = bb >> 7; const int rem = bb & 127;
        bx = rem & 15; by = rem >> 4; R = 256; C = 512; in = W1; out = w1t;
    } else if (b < 7168) {
        const int bb = b - 5120; e = bb >> 8; const int rem = bb & 255;
        bx = rem & 15; by = rem >> 4; R = 512; C = 512; in = W2; out = w2t;
    } else {
        const int bb = b - 7168; e = bb >> 4; bx = 0; by = bb & 15;
        R = 512; C = 32; in = W3; out = w3t;
    }
    const int r0 = by * 32, c0 = bx * 32;
    const float* ine = in + (size_t)e * R * C;
    uint16_t* oute   = out + (size_t)e * R * C;
#pragma unroll
    for (int j = 0; j < 4; ++j)
        t[ty + 8 * j][tx] = ine[(size_t)(r0 + ty + 8 * j) * C + (c0 + tx)];
    __syncthreads();
#pragma unroll
    for (int j = 0; j < 4; ++j) {
        const int orow = c0 + ty + 8 * j;
        const int ocol = r0 + tx;
        oute[(size_t)orow * R + ocol] = f2bf(t[tx][ty + 8 * j]);
    }
}

// =====================================================================
// 8-PHASE GEMM (m201-template port). 256x256 tile, BK=64, 8 waves
// (wm=wid>>2, wn=wid&3). Per-wave: 8 A-frags (batch) x 4 W-frags (ncol).
// LDS = ring of 8 half-tile slots x 16KB (tile T dbuf d=T&1):
//   slot d*4+j   = W half j (rows j*128..)      [wave reads half wn>>1]
//   slot d*4+2+j = A half j (rows j*128..)      [wave reads half wm]
// Phase p (1..4) of tile T:
//   top: ds_read frags for THIS phase (p1: 8 W-b128 + 4 A-b128; else 4)
//   stage ONE half-tile (2 gload16/wave), consumed-order lag:
//     p1:A0(T+1)  p2:A1(T+1)  p3:W0(T+2)  p4:W1(T+2)
//     (every slot overwrite is >=2 barriers after its last read)
//   s_barrier; lgkmcnt(0); setprio(1); 16 MFMA; setprio(0);
//   p4 only: vmcnt gate for tile T+1 BEFORE the end barrier
//     (gate->barrier->reads = cross-wave visibility; per-wave issue
//      sequence leaves exactly W0,W1(T+2)=4 loads in flight -> vmcnt(4);
//      before the last tile -> vmcnt(0)); s_barrier.
// Prologue: stage W0,W1,A0,A1(t0), W0,W1(t1); vmcnt(4); barrier.
// vmcnt is PER-WAVE: each stage-call = 1 outstanding load (r11 lesson).
// Both-sides 16B-slot XOR swizzle (r7-verified: conflicts == 0).
// Swapped MFMA: D = mfma(A=W frag [n][k], B=act frag [m][k])
//   -> D col(lane&15)=batch row, row(kg*4+v)=out col.
// =====================================================================
template <int K>
__global__ __launch_bounds__(512, 1) void gemm8p(
    const uint16_t* __restrict__ Act,   // + e*actEStride, [Mc][K]
    size_t actEStride,                  // 0 when shared across e (layer 1)
    const uint16_t* __restrict__ Wt,    // [8][512][K] bf16 (n-major, k-contig)
    const float* __restrict__ bias,     // [8][512]
    uint16_t* __restrict__ Out,         // + e*outEStride, [Mc][512] bf16 (relu'd)
    size_t outEStride)
{
    extern __shared__ char smem[];      // 8 x 16KB half-tile ring
    const int tid = threadIdx.x, wid = tid >> 6, lane = tid & 63;
    const int kg = lane >> 4, lr = lane & 15;
    const int e   = blockIdx.x;
    const int nb0 = blockIdx.y * 256;
    const int m0  = blockIdx.z * 256;
    const int wm = wid >> 2, wn = wid & 3;

    const uint16_t* Wbase = Wt  + ((size_t)e * 512 + nb0) * K;
    const uint16_t* Abase = Act + (size_t)e * actEStride + (size_t)m0 * K;
    uint16_t* Obase       = Out + (size_t)e * outEStride;

    const int rlo = lane >> 3, pslot = lane & 7;
    const int lswz = (pslot ^ rlo) * 8;            // pre-swizzled source k-offset

    auto stageHalf = [&](const uint16_t* base, int slot, int half0, int ks) {
#pragma unroll
        for (int i = 0; i < 2; ++i) {
            const int row = half0 + wid * 16 + i * 8 + rlo;   // row&7 == rlo
            gload16(base + (size_t)row * K + ks + lswz,
                    smem + slot * 16384 + (wid * 16 + i * 8) * 128 + lane * 16);
        }
    };
    auto stageW = [&](int j, int T) { stageHalf(Wbase, (T & 1) * 4 + j,     j * 128, T * 64); };
    auto stageA = [&](int j, int T) { stageHalf(Abase, (T & 1) * 4 + 2 + j, j * 128, T * 64); };

    f32x4 acc[8][4];
#pragma unroll
    for (int b = 0; b < 8; ++b)
#pragma unroll
        for (int c = 0; c < 4; ++c) acc[b][c] = f32x4{0.f, 0.f, 0.f, 0.f};

    constexpr int NT = K / 64;           // 4 (K=256) or 8 (K=512)
    // ---- prologue: 6 half-tiles (12 loads/wave), gate to 4 in flight ----
    stageW(0, 0); stageW(1, 0); stageA(0, 0); stageA(1, 0);
    stageW(0, 1); stageW(1, 1);
    asm volatile("s_waitcnt vmcnt(4)" ::: "memory");   // tile0 fully landed
    __builtin_amdgcn_s_barrier();

    const int swz = lr & 7;
#pragma unroll
    for (int T = 0; T < NT; ++T) {
        const int d = T & 1;
        const char* sW = smem + (d * 4 + (wn >> 1)) * 16384;
        const char* sA = smem + (d * 4 + 2 + wm) * 16384;
        bf16x8 wf[4][2];
#pragma unroll
        for (int p = 1; p <= 4; ++p) {
            if (p == 1) {
#pragma unroll
                for (int c = 0; c < 4; ++c)
#pragma unroll
                    for (int kh = 0; kh < 2; ++kh)
                        wf[c][kh] = *(const bf16x8*)(sW + ((wn & 1) * 64 + c * 16 + lr) * 128 +
                                                     (((kh * 4 + kg) ^ swz) << 4));
            }
            bf16x8 af[2][2];
#pragma unroll
            for (int i = 0; i < 2; ++i)
#pragma unroll
                for (int kh = 0; kh < 2; ++kh)
                    af[i][kh] = *(const bf16x8*)(sA + ((2 * (p - 1) + i) * 16 + lr) * 128 +
                                                 (((kh * 4 + kg) ^ swz) << 4));
            if (p == 1 && T + 1 < NT) stageA(0, T + 1);
            if (p == 2 && T + 1 < NT) stageA(1, T + 1);
            if (p == 3 && T + 2 < NT) stageW(0, T + 2);
            if (p == 4 && T + 2 < NT) stageW(1, T + 2);

            __builtin_amdgcn_s_barrier();
            asm volatile("s_waitcnt lgkmcnt(0)" ::: "memory");
            __builtin_amdgcn_s_setprio(1);
#pragma unroll
            for (int i = 0; i < 2; ++i)
#pragma unroll
                for (int c = 0; c < 4; ++c)
#pragma unroll
                    for (int kh = 0; kh < 2; ++kh)
                        acc[2 * (p - 1) + i][c] = __builtin_amdgcn_mfma_f32_16x16x32_bf16(
                            wf[c][kh], af[i][kh], acc[2 * (p - 1) + i][c], 0, 0, 0);
            __builtin_amdgcn_s_setprio(0);
            if (p == 4 && T + 1 < NT) {
                if (T + 2 < NT) asm volatile("s_waitcnt vmcnt(4)" ::: "memory");
                else            asm volatile("s_waitcnt vmcnt(0)" ::: "memory");
            }
            __builtin_amdgcn_s_barrier();
        }
    }

    // ---- epilogue: bias + relu -> bf16, 8B stores (r12-verified) ----
#pragma unroll
    for (int c = 0; c < 4; ++c) {
        const int col = nb0 + wn * 64 + c * 16 + kg * 4;
        const float4 bv = *(const float4*)(bias + e * 512 + col);
#pragma unroll
        for (int b = 0; b < 8; ++b) {
            const float x0 = fmaxf(acc[b][c][0] + bv.x, 0.f);
            const float x1 = fmaxf(acc[b][c][1] + bv.y, 0.f);
            const float x2 = fmaxf(acc[b][c][2] + bv.z, 0.f);
            const float x3 = fmaxf(acc[b][c][3] + bv.w, 0.f);
            uint2 w;
            w.x = pk2bf(x0, x1);
            w.y = pk2bf(x2, x3);
            const int row = m0 + wm * 128 + b * 16 + lr;
            *(uint2*)(Obase + (size_t)row * 512 + col) = w;
        }
    }
}

// ---- layer 3: Mc x 32, K=512; r12-verified 2-phase (small, ~10us) ----
__global__ __launch_bounds__(256, 4) void gemm_o(
    const uint16_t* __restrict__ Act, size_t actEStride,
    const uint16_t* __restrict__ W3t, const float* __restrict__ b3,
    float* __restrict__ Out)
{
    __shared__ char smem[40960];
    const int tid = threadIdx.x, wid = tid >> 6, lane = tid & 63;
    const int kg = lane >> 4, lr = lane & 15;
    const int e  = blockIdx.x;
    const int m0 = blockIdx.z * 128;

    const uint16_t* Abase = Act + (size_t)e * actEStride + (size_t)m0 * 512;
    const uint16_t* Bbase = W3t + (size_t)e * 32 * 512;

    f32x4 acc[2][2];
#pragma unroll
    for (int i = 0; i < 2; ++i)
#pragma unroll
        for (int j = 0; j < 2; ++j) acc[i][j] = f32x4{0.f, 0.f, 0.f, 0.f};

    const int rlo = lane >> 3, pslot = lane & 7;
    const int lswz = (pslot ^ rlo) * 8;

    auto STAGE = [&](int p, int ks) {
#pragma unroll
        for (int i = 0; i < 4; ++i) {
            const int g   = wid * 4 + i;
            const int row = g * 8 + rlo;
            gload16(Abase + (size_t)row * 512 + ks + lswz, smem + p * 20480 + g * 1024);
        }
        const int row = wid * 8 + rlo;
        gload16(Bbase + (size_t)row * 512 + ks + lswz, smem + p * 20480 + 16384 + wid * 1024);
    };

    STAGE(0, 0);
    __syncthreads();

#pragma unroll
    for (int t = 0; t < 8; ++t) {
        const int cur = t & 1;
        if (t + 1 < 8)
            STAGE(1 - cur, (t + 1) * 64);
        asm volatile("" ::: "memory");

        const char* sA = smem + cur * 20480;
        const char* sB = sA + 16384;
        __builtin_amdgcn_s_setprio(1);
#pragma unroll
        for (int h = 0; h < 2; ++h) {
            bf16x8 a[2], b[2];
#pragma unroll
            for (int i = 0; i < 2; ++i) {
                const int rowA = wid * 32 + i * 16 + lr;
                a[i] = *(const bf16x8*)(sA + rowA * 128 + (((4 * h + kg) ^ (rowA & 7)) << 4));
                const int rowB = i * 16 + lr;
                b[i] = *(const bf16x8*)(sB + rowB * 128 + (((4 * h + kg) ^ (rowB & 7)) << 4));
            }
#pragma unroll
            for (int af = 0; af < 2; ++af)
#pragma unroll
                for (int bf = 0; bf < 2; ++bf)
                    acc[af][bf] = __builtin_amdgcn_mfma_f32_16x16x32_bf16(a[af], b[bf], acc[af][bf], 0, 0, 0);
        }
        __builtin_amdgcn_s_setprio(0);
        __syncthreads();
    }

#pragma unroll
    for (int af = 0; af < 2; ++af)
#pragma unroll
        for (int bf = 0; bf < 2; ++bf) {
            const float bb = b3[e * 32 + bf * 16 + lr];
#pragma unroll
            for (int v = 0; v < 4; ++v) {
                const int row = m0 + wid * 32 + af * 16 + kg * 4 + v;
                Out[(size_t)row * 256 + e * 32 + bf * 16 + lr] = acc[af][bf][v] + bb;
            }
        }
}

// =====================================================================
// Fallback (round-3 fused kernel) — only if ws too small.
// =====================================================================
template <int K, bool B_LDS>
__device__ __forceinline__ void layer128(
    const uint16_t* __restrict__ Aw, const uint16_t* __restrict__ Bg,
    const char* __restrict__ Bl, const float* __restrict__ bias,
    char* __restrict__ ldsOut, int n0, int kg, int lr, bool syncBeforeEpi) {
    f32x4 acc[8][4];
#pragma unroll
    for (int m = 0; m < 8; ++m)
#pragma unroll
        for (int n = 0; n < 4; ++n) acc[m][n] = f32x4{0.f, 0.f, 0.f, 0.f};
    auto ldA = [&](int mf, int k0) -> bf16x8 {
        return *(const bf16x8*)(Aw + (size_t)(mf * 16 + lr) * K + k0 + kg * 8);
    };
    auto ldB = [&](int nf, int k0) -> bf16x8 {
        if constexpr (B_LDS) {
            const int row = nf * 16 + lr;
            return *(const bf16x8*)(Bl + row * 1024 +
                                    ((((k0 + kg * 8) << 1)) ^ ((row & 7) << 4)));
        } else {
            return *(const bf16x8*)(Bg + (size_t)(nf * 16 + lr) * K + k0 + kg * 8);
        }
    };
    bf16x8 a0[8], b0[4], a1[8], b1[4];
#pragma unroll
    for (int i = 0; i < 8; ++i) a0[i] = ldA(i, 0);
#pragma unroll
    for (int i = 0; i < 4; ++i) b0[i] = ldB(i, 0);
#pragma unroll
    for (int k0 = 0; k0 < K; k0 += 64) {
#pragma unroll
        for (int i = 0; i < 8; ++i) a1[i] = ldA(i, k0 + 32);
#pragma unroll
        for (int i = 0; i < 4; ++i) b1[i] = ldB(i, k0 + 32);
#pragma unroll
        for (int m = 0; m < 8; ++m)
#pragma unroll
            for (int n = 0; n < 4; ++n)
                acc[m][n] = __builtin_amdgcn_mfma_f32_16x16x32_bf16(a0[m], b0[n], acc[m][n], 0, 0, 0);
        if (k0 + 64 < K) {
#pragma unroll
            for (int i = 0; i < 8; ++i) a0[i] = ldA(i, k0 + 64);
#pragma unroll
            for (int i = 0; i < 4; ++i) b0[i] = ldB(i, k0 + 64);
        }
#pragma unroll
        for (int m = 0; m < 8; ++m)
#pragma unroll
            for (int n = 0; n < 4; ++n)
                acc[m][n] = __builtin_amdgcn_mfma_f32_16x16x32_bf16(a1[m], b1[n], acc[m][n], 0, 0, 0);
    }
    if (syncBeforeEpi) __syncthreads();
#pragma unroll
    for (int mf = 0; mf < 8; ++mf) {
        const float4 bv = *(const float4*)(bias + mf * 16 + kg * 4);
#pragma unroll
        for (int nf = 0; nf < 4; ++nf) {
            float x0 = fmaxf(acc[mf][nf][0] + bv.x, 0.f);
            float x1 = fmaxf(acc[mf][nf][1] + bv.y, 0.f);
            float x2 = fmaxf(acc[mf][nf][2] + bv.z, 0.f);
            float x3 = fmaxf(acc[mf][nf][3] + bv.w, 0.f);
            uint2 w;
            w.x = pk2bf(x0, x1);
            w.y = pk2bf(x2, x3);
            const int row = nf * 16 + lr;
            const int colbyte = (n0 + mf * 16 + kg * 4) << 1;
            *(uint2*)(ldsOut + row * 1024 + (colbyte ^ ((row & 7) << 4))) = w;
        }
    }
}

__global__ __launch_bounds__(256, 2) void fused_mlp(
    const uint16_t* __restrict__ Xbf,
    const uint16_t* __restrict__ W1T, const float* __restrict__ b1,
    const uint16_t* __restrict__ W2T, const float* __restrict__ b2,
    const uint16_t* __restrict__ W3T, const float* __restrict__ b3,
    float* __restrict__ out) {
    extern __shared__ char hbuf[];
    const int tid = threadIdx.x, wid = tid >> 6, lane = tid & 63;
    const int kg = lane >> 4, lr = lane & 15;
    const int e  = blockIdx.x & 7;
    const int b0 = (blockIdx.x >> 3) * 64;
    const int n0 = wid * 128;
    layer128<256, false>(W1T + ((size_t)e * 512 + n0) * 256, Xbf + (size_t)b0 * 256,
                         nullptr, b1 + e * 512 + n0, hbuf, n0, kg, lr, false);
    __syncthreads();
    layer128<512, true>(W2T + ((size_t)e * 512 + n0) * 512, nullptr, hbuf,
                        b2 + e * 512 + n0, hbuf, n0, kg, lr, true);
    __syncthreads();
    {
        const int rowB  = wid * 16 + lr;
        const int bbyte = rowB * 1024;
        const int bswz  = (rowB & 7) << 4;
        const uint16_t* W3e = W3T + (size_t)e * 32 * 512;
        f32x4 acc[2];
        acc[0] = f32x4{0.f, 0.f, 0.f, 0.f};
        acc[1] = f32x4{0.f, 0.f, 0.f, 0.f};
#pragma unroll
        for (int k0 = 0; k0 < 512; k0 += 32) {
            bf16x8 a = *(const bf16x8*)(hbuf + bbyte + ((((k0 + kg * 8) << 1)) ^ bswz));
#pragma unroll
            for (int nf = 0; nf < 2; ++nf) {
                bf16x8 b = *(const bf16x8*)(W3e + (size_t)(nf * 16 + lr) * 512 + k0 + kg * 8);
                acc[nf] = __builtin_amdgcn_mfma_f32_16x16x32_bf16(a, b, acc[nf], 0, 0, 0);
            }
        }
#pragma unroll
        for (int nf = 0; nf < 2; ++nf) {
            const float bb = b3[e * 32 + nf * 16 + lr];
#pragma unroll
            for (int v = 0; v < 4; ++v) {
                const int row = b0 + wid * 16 + kg * 4 + v;
                out[(size_t)row * 256 + e * 32 + nf * 16 + lr] = acc[nf][v] + bb;
            }
        }
    }
}

// ---------------- host launch ----------------
extern "C" void kernel_launch(void* const* d_in, const int* in_sizes, int n_in,
                              void* d_out, int out_size, void* d_ws, size_t ws_size,
                              hipStream_t stream) {
    (void)in_sizes; (void)n_in; (void)out_size;
    const float* X  = (const float*)d_in[0];   // [16384,256]
    const float* W1 = (const float*)d_in[1];   // [8,256,512]
    const float* b1 = (const float*)d_in[2];   // [8,512]
    const float* W2 = (const float*)d_in[3];   // [8,512,512]
    const float* b2 = (const float*)d_in[4];   // [8,512]
    const float* W3 = (const float*)d_in[5];   // [8,512,32]
    const float* b3 = (const float*)d_in[6];   // [8,32]
    float* out = (float*)d_out;                // [16384,8,32]

    uint16_t* w1t = (uint16_t*)d_ws;           // [8][512][256] bf16
    uint16_t* w2t = w1t + 8 * 256 * 512;       // [8][512][512] bf16
    uint16_t* w3t = w2t + 8 * 512 * 512;       // [8][32][512]  bf16
    uint16_t* xbf = w3t + 8 * 512 * 32;        // [16384][256]  bf16
    uint16_t* h1  = xbf + (size_t)16384 * 256; // [8][Mc][512] bf16, e-major
    const size_t FIXED_BYTES = ((size_t)(8 * 256 * 512) + 8 * 512 * 512 + 8 * 32 * 512 +
                                (size_t)16384 * 256) * 2;   // 14,942,208

    int Mc = 0;
    for (int cand = 16384; cand >= 2048; cand >>= 1) {
        if (ws_size >= FIXED_BYTES + (size_t)16384 * cand) { Mc = cand; break; }
    }

    prep<<<7296, 256, 0, stream>>>(X, W1, W2, W3, xbf, w1t, w2t, w3t);

    if (Mc > 0) {
        uint16_t* h2 = h1 + (size_t)8 * Mc * 512;
        const size_t eStr = (size_t)Mc * 512;
        (void)hipFuncSetAttribute((const void*)gemm8p<256>,
                                  hipFuncAttributeMaxDynamicSharedMemorySize, 131072);
        (void)hipFuncSetAttribute((const void*)gemm8p<512>,
                                  hipFuncAttributeMaxDynamicSharedMemorySize, 131072);
        for (int c0 = 0; c0 < 16384; c0 += Mc) {
            gemm8p<256><<<dim3(8, 2, Mc / 256), 512, 131072, stream>>>(
                xbf + (size_t)c0 * 256, 0, w1t, b1, h1, eStr);
            gemm8p<512><<<dim3(8, 2, Mc / 256), 512, 131072, stream>>>(
                h1, eStr, w2t, b2, h2, eStr);
            gemm_o<<<dim3(8, 1, Mc / 128), 256, 0, stream>>>(
                h2, eStr, w3t, b3, out + (size_t)c0 * 256);
        }
    } else {
        (void)hipFuncSetAttribute((const void*)fused_mlp,
                                  hipFuncAttributeMaxDynamicSharedMemorySize, 65536);
        fused_mlp<<<2048, 256, 65536, stream>>>(xbf, w1t, b1, w2t, b2, w3t, b3, out);
    }
}

// Round 15
// 174.188 us; speedup vs baseline: 1.2161x; 1.1679x over previous
//
#include <hip/hip_runtime.h>
#include <stdint.h>

// ---------------- types ----------------
typedef short bf16x8 __attribute__((ext_vector_type(8)));
typedef float f32x4  __attribute__((ext_vector_type(4)));

__device__ __forceinline__ uint16_t f2bf(float f) {
    uint32_t u = __float_as_uint(f);
    u += 0x7FFF + ((u >> 16) & 1);   // round-to-nearest-even
    return (uint16_t)(u >> 16);
}
__device__ __forceinline__ uint32_t pk2bf(float a, float b) {
    return (uint32_t)f2bf(a) | ((uint32_t)f2bf(b) << 16);
}

typedef __attribute__((address_space(1))) const uint32_t gu32;
typedef __attribute__((address_space(3))) uint32_t lu32;
__device__ __forceinline__ void gload16(const void* g, void* l) {
    // async global->LDS, 16B/lane (one call stages 1KB per wave)
    __builtin_amdgcn_global_load_lds((gu32*)g, (lu32*)l, 16, 0, 0);
}

// =====================================================================
// prep: all prologue work in one kernel (r13/r14-verified).
// =====================================================================
__global__ __launch_bounds__(256) void prep(
    const float* __restrict__ X,  const float* __restrict__ W1,
    const float* __restrict__ W2, const float* __restrict__ W3,
    uint16_t* __restrict__ xbf, uint16_t* __restrict__ w1t,
    uint16_t* __restrict__ w2t, uint16_t* __restrict__ w3t)
{
    const int b = blockIdx.x, tid = threadIdx.x;
    if (b < 4096) {                       // cvt X
        const int i = b * 256 + tid;
        const float4 v = ((const float4*)X)[i];
        ushort4 h;
        h.x = f2bf(v.x); h.y = f2bf(v.y); h.z = f2bf(v.z); h.w = f2bf(v.w);
        ((ushort4*)xbf)[i] = h;
        return;
    }
    __shared__ float t[32][33];
    const int tx = tid & 31, ty = tid >> 5;
    const float* in; uint16_t* out; int R, C, bx, by, e;
    if (b < 5120) {
        const int bb = b - 4096; e = bb >> 7; const int rem = bb & 127;
        bx = rem & 15; by = rem >> 4; R = 256; C = 512; in = W1; out = w1t;
    } else if (b < 7168) {
        const int bb = b - 5120; e = bb >> 8; const int rem = bb & 255;
        bx = rem & 15; by = rem >> 4; R = 512; C = 512; in = W2; out = w2t;
    } else {
        const int bb = b - 7168; e = bb >> 4; bx = 0; by = bb & 15;
        R = 512; C = 32; in = W3; out = w3t;
    }
    const int r0 = by * 32, c0 = bx * 32;
    const float* ine = in + (size_t)e * R * C;
    uint16_t* oute   = out + (size_t)e * R * C;
#pragma unroll
    for (int j = 0; j < 4; ++j)
        t[ty + 8 * j][tx] = ine[(size_t)(r0 + ty + 8 * j) * C + (c0 + tx)];
    __syncthreads();
#pragma unroll
    for (int j = 0; j < 4; ++j) {
        const int orow = c0 + ty + 8 * j;
        const int ocol = r0 + tx;
        oute[(size_t)orow * R + ocol] = f2bf(t[tx][ty + 8 * j]);
    }
}

// =====================================================================
// fused64: ALL THREE LAYERS per block. Block = 64 batch rows x one e.
// 8 waves (512 thr). Grid (8e, 256) -> XCD = e (weights L2-pinned).
// LDS 160KB: [0,64K) h1 [64][512] bf16 swz | [64K,128K) W-stage dbuf
// 2x32KB | [128K,160K) scratch: X [4kt][64][64] then h2half [64][256].
// h1/h2 NEVER touch global (was 536MB of L2/L3 traffic = the r6-r14
// 205us wall). Weights stream from XCD-local L2 (0.77MB/e resident).
// Engine = r12-verified 2-phase (STAGE next -> compute -> __syncthreads,
// full-drain gate, race-free). Swizzle: byte = row*stride +
// ((colbyte) ^ ((row&7)<<4)) both sides (r7-verified, conflicts==0).
// L1/L2 swapped MFMA: D = mfma(W frag [n][k], act frag [m][k]) ->
//   col(lane&15)=batch row, row(kg*4+v)=out col (r6+-verified).
// L2->L3 in-LDS handoff per n-half = r10-verified l23 pattern.
// =====================================================================
__global__ __launch_bounds__(512, 1) void fused64(
    const uint16_t* __restrict__ xbf,
    const uint16_t* __restrict__ W1t, const float* __restrict__ b1,
    const uint16_t* __restrict__ W2t, const float* __restrict__ b2,
    const uint16_t* __restrict__ W3t, const float* __restrict__ b3,
    float* __restrict__ out)
{
    extern __shared__ char smem[];
    char* h1buf = smem;             // 64KB  [64][512] bf16, stride 1024B
    char* wstg  = smem + 65536;     // 64KB  dbuf 2 x [256][64] bf16
    char* scr   = smem + 131072;    // 32KB  X 4x[64][64] / h2half [64][256]

    const int tid = threadIdx.x, wid = tid >> 6, lane = tid & 63;
    const int kg = lane >> 4, lr = lane & 15;
    const int e   = blockIdx.x;
    const int bm0 = blockIdx.y * 64;
    const int rlo = lane >> 3, pslot = lane & 7;
    const int lswz = (pslot ^ rlo) * 8;           // pre-swizzled source k-off

    const uint16_t* Xb  = xbf + (size_t)bm0 * 256;
    const uint16_t* W1e = W1t + (size_t)e * 512 * 256;
    const uint16_t* W2e = W2t + (size_t)e * 512 * 512;
    const uint16_t* W3e = W3t + (size_t)e * 32 * 512;

    // stage one W-tile [256 n][64 k] (32KB) into wstg[cur]; 4 gloads/wave
    auto stageW = [&](const uint16_t* Wb, int cur, int kt, int K) {
#pragma unroll
        for (int i = 0; i < 4; ++i) {
            const int r = wid * 32 + i * 8 + rlo;           // r&7 == rlo
            gload16(Wb + (size_t)r * K + kt * 64 + lswz,
                    wstg + cur * 32768 + (wid * 32 + i * 8) * 128 + lane * 16);
        }
    };

    // ---- prologue: stage X tile [64][256] as 4 ktiles + W1(half0,kt0) ----
#pragma unroll
    for (int kt = 0; kt < 4; ++kt) {
        const int r = wid * 8 + rlo;                        // rows wid*8..+7
        gload16(Xb + (size_t)r * 256 + kt * 64 + lswz,
                scr + kt * 8192 + (wid * 8) * 128 + lane * 16);
    }

    f32x4 oacc = f32x4{0.f, 0.f, 0.f, 0.f};    // L3 accum (wave's 1 frag)
    const int mf = wid >> 1, of = wid & 1;      // L3 wave split: 4m x 2o

    // ================= LAYER 1: h1 = relu(X @ W1 + b1), K=256 =========
#pragma unroll
    for (int half = 0; half < 2; ++half) {
        const uint16_t* Wb = W1e + (size_t)(half * 256) * 256;
        stageW(Wb, 0, 0, 256);
        __syncthreads();                         // X + W-tile0 ready

        f32x4 acc[4][2];
#pragma unroll
        for (int b = 0; b < 4; ++b)
#pragma unroll
            for (int c = 0; c < 2; ++c) acc[b][c] = f32x4{0.f, 0.f, 0.f, 0.f};

#pragma unroll
        for (int kt = 0; kt < 4; ++kt) {
            const int cur = kt & 1;
            if (kt + 1 < 4) stageW(Wb, 1 - cur, kt + 1, 256);
            asm volatile("" ::: "memory");
            __builtin_amdgcn_s_setprio(1);
#pragma unroll
            for (int kh = 0; kh < 2; ++kh) {
                bf16x8 wf[2], af[4];
#pragma unroll
                for (int c = 0; c < 2; ++c) {
                    const int row = wid * 32 + c * 16 + lr;
                    wf[c] = *(const bf16x8*)(wstg + cur * 32768 + row * 128 +
                                             (((kh * 4 + kg) ^ (row & 7)) << 4));
                }
#pragma unroll
                for (int b = 0; b < 4; ++b) {
                    const int row = b * 16 + lr;
                    af[b] = *(const bf16x8*)(scr + kt * 8192 + row * 128 +
                                             (((kh * 4 + kg) ^ (row & 7)) << 4));
                }
#pragma unroll
                for (int b = 0; b < 4; ++b)
#pragma unroll
                    for (int c = 0; c < 2; ++c)
                        acc[b][c] = __builtin_amdgcn_mfma_f32_16x16x32_bf16(wf[c], af[b], acc[b][c], 0, 0, 0);
            }
            __builtin_amdgcn_s_setprio(0);
            __syncthreads();                     // drain prefetch + publish
        }

        // epilogue: bias+relu -> h1buf[:, half*256 + wid*32 ..]
#pragma unroll
        for (int c = 0; c < 2; ++c) {
            const int col = half * 256 + wid * 32 + c * 16 + kg * 4;
            const float4 bv = *(const float4*)(b1 + e * 512 + col);
#pragma unroll
            for (int b = 0; b < 4; ++b) {
                const float x0 = fmaxf(acc[b][c][0] + bv.x, 0.f);
                const float x1 = fmaxf(acc[b][c][1] + bv.y, 0.f);
                const float x2 = fmaxf(acc[b][c][2] + bv.z, 0.f);
                const float x3 = fmaxf(acc[b][c][3] + bv.w, 0.f);
                uint2 w;
                w.x = pk2bf(x0, x1);
                w.y = pk2bf(x2, x3);
                const int row = b * 16 + lr;
                *(uint2*)(h1buf + row * 1024 + ((col << 1) ^ ((row & 7) << 4))) = w;
            }
        }
        __syncthreads();                         // h1 half visible; wstg free
    }

    // ========== LAYERS 2+3: per n-half, h2half in scr, L3 partial ======
#pragma unroll
    for (int half = 0; half < 2; ++half) {
        const uint16_t* Wb = W2e + (size_t)(half * 256) * 512;
        stageW(Wb, 0, 0, 512);
        __syncthreads();

        f32x4 acc[4][2];
#pragma unroll
        for (int b = 0; b < 4; ++b)
#pragma unroll
            for (int c = 0; c < 2; ++c) acc[b][c] = f32x4{0.f, 0.f, 0.f, 0.f};

#pragma unroll
        for (int kt = 0; kt < 8; ++kt) {
            const int cur = kt & 1;
            if (kt + 1 < 8) stageW(Wb, 1 - cur, kt + 1, 512);
            asm volatile("" ::: "memory");
            __builtin_amdgcn_s_setprio(1);
#pragma unroll
            for (int kh = 0; kh < 2; ++kh) {
                bf16x8 wf[2], af[4];
#pragma unroll
                for (int c = 0; c < 2; ++c) {
                    const int row = wid * 32 + c * 16 + lr;
                    wf[c] = *(const bf16x8*)(wstg + cur * 32768 + row * 128 +
                                             (((kh * 4 + kg) ^ (row & 7)) << 4));
                }
                const int kbyte = (kt * 64 + kh * 32 + kg * 8) << 1;
#pragma unroll
                for (int b = 0; b < 4; ++b) {
                    const int row = b * 16 + lr;
                    af[b] = *(const bf16x8*)(h1buf + row * 1024 +
                                             (kbyte ^ ((row & 7) << 4)));
                }
#pragma unroll
                for (int b = 0; b < 4; ++b)
#pragma unroll
                    for (int c = 0; c < 2; ++c)
                        acc[b][c] = __builtin_amdgcn_mfma_f32_16x16x32_bf16(wf[c], af[b], acc[b][c], 0, 0, 0);
            }
            __builtin_amdgcn_s_setprio(0);
            __syncthreads();
        }

        // epilogue: bias+relu -> h2half in scr [64][256], stride 512B
#pragma unroll
        for (int c = 0; c < 2; ++c) {
            const int colh = wid * 32 + c * 16 + kg * 4;        // 0..255
            const float4 bv = *(const float4*)(b2 + e * 512 + half * 256 + colh);
#pragma unroll
            for (int b = 0; b < 4; ++b) {
                const float x0 = fmaxf(acc[b][c][0] + bv.x, 0.f);
                const float x1 = fmaxf(acc[b][c][1] + bv.y, 0.f);
                const float x2 = fmaxf(acc[b][c][2] + bv.z, 0.f);
                const float x3 = fmaxf(acc[b][c][3] + bv.w, 0.f);
                uint2 w;
                w.x = pk2bf(x0, x1);
                w.y = pk2bf(x2, x3);
                const int row = b * 16 + lr;
                *(uint2*)(scr + row * 512 + ((colh << 1) ^ ((row & 7) << 4))) = w;
            }
        }
        __syncthreads();                         // h2half visible

        // L3 partial: oacc += h2half @ W3[:, half*256..+256)
        // swapped: D=mfma(W3 frag [o][k], h2 frag [m][k]) ->
        //   col(lane&15)=m-row, row(kg*4+v)=o-col  (r10-verified)
#pragma unroll
        for (int kc = 0; kc < 8; ++kc) {
            const int row = mf * 16 + lr;
            const bf16x8 hb = *(const bf16x8*)(scr + row * 512 +
                                               (((kc * 32 + kg * 8) << 1) ^ ((row & 7) << 4)));
            const bf16x8 w3 = *(const bf16x8*)(W3e + (size_t)(of * 16 + lr) * 512 +
                                               half * 256 + kc * 32 + kg * 8);
            oacc = __builtin_amdgcn_mfma_f32_16x16x32_bf16(w3, hb, oacc, 0, 0, 0);
        }
        __syncthreads();                         // h2half consumed; scr free
    }

    // ---- final store: bias3 + float4, row-contiguous (r10-verified) ----
    {
        const int col = e * 32 + of * 16 + kg * 4;
        const float4 bv = *(const float4*)(b3 + col);
        const int row = bm0 + mf * 16 + lr;
        float4 res;
        res.x = oacc[0] + bv.x;
        res.y = oacc[1] + bv.y;
        res.z = oacc[2] + bv.z;
        res.w = oacc[3] + bv.w;
        *(float4*)(out + (size_t)row * 256 + col) = res;
    }
}

// ---------------- host launch ----------------
extern "C" void kernel_launch(void* const* d_in, const int* in_sizes, int n_in,
                              void* d_out, int out_size, void* d_ws, size_t ws_size,
                              hipStream_t stream) {
    (void)in_sizes; (void)n_in; (void)out_size; (void)ws_size;
    const float* X  = (const float*)d_in[0];   // [16384,256]
    const float* W1 = (const float*)d_in[1];   // [8,256,512]
    const float* b1 = (const float*)d_in[2];   // [8,512]
    const float* W2 = (const float*)d_in[3];   // [8,512,512]
    const float* b2 = (const float*)d_in[4];   // [8,512]
    const float* W3 = (const float*)d_in[5];   // [8,512,32]
    const float* b3 = (const float*)d_in[6];   // [8,32]
    float* out = (float*)d_out;                // [16384,8,32]

    uint16_t* w1t = (uint16_t*)d_ws;           // [8][512][256] bf16  (2 MB)
    uint16_t* w2t = w1t + 8 * 256 * 512;       // [8][512][512] bf16  (4 MB)
    uint16_t* w3t = w2t + 8 * 512 * 512;       // [8][32][512]  bf16  (256 KB)
    uint16_t* xbf = w3t + 8 * 512 * 32;        // [16384][256]  bf16  (8 MB)

    prep<<<7296, 256, 0, stream>>>(X, W1, W2, W3, xbf, w1t, w2t, w3t);

    (void)hipFuncSetAttribute((const void*)fused64,
                              hipFuncAttributeMaxDynamicSharedMemorySize, 163840);
    fused64<<<dim3(8, 256), 512, 163840, stream>>>(xbf, w1t, b1, w2t, b2,
                                                   w3t, b3, out);
}

// Round 16
// 145.036 us; speedup vs baseline: 1.4606x; 1.2010x over previous
//
#include <hip/hip_runtime.h>
#include <stdint.h>

// ---------------- types ----------------
typedef short bf16x8 __attribute__((ext_vector_type(8)));
typedef float f32x4  __attribute__((ext_vector_type(4)));

__device__ __forceinline__ uint16_t f2bf(float f) {
    uint32_t u = __float_as_uint(f);
    u += 0x7FFF + ((u >> 16) & 1);   // round-to-nearest-even
    return (uint16_t)(u >> 16);
}
__device__ __forceinline__ uint32_t pk2bf(float a, float b) {
    return (uint32_t)f2bf(a) | ((uint32_t)f2bf(b) << 16);
}

typedef __attribute__((address_space(1))) const uint32_t gu32;
typedef __attribute__((address_space(3))) uint32_t lu32;
__device__ __forceinline__ void gload16(const void* g, void* l) {
    __builtin_amdgcn_global_load_lds((gu32*)g, (lu32*)l, 16, 0, 0);
}

// =====================================================================
// prep: all prologue work in one kernel (r13-15-verified).
// =====================================================================
__global__ __launch_bounds__(256) void prep(
    const float* __restrict__ X,  const float* __restrict__ W1,
    const float* __restrict__ W2, const float* __restrict__ W3,
    uint16_t* __restrict__ xbf, uint16_t* __restrict__ w1t,
    uint16_t* __restrict__ w2t, uint16_t* __restrict__ w3t)
{
    const int b = blockIdx.x, tid = threadIdx.x;
    if (b < 4096) {
        const int i = b * 256 + tid;
        const float4 v = ((const float4*)X)[i];
        ushort4 h;
        h.x = f2bf(v.x); h.y = f2bf(v.y); h.z = f2bf(v.z); h.w = f2bf(v.w);
        ((ushort4*)xbf)[i] = h;
        return;
    }
    __shared__ float t[32][33];
    const int tx = tid & 31, ty = tid >> 5;
    const float* in; uint16_t* out; int R, C, bx, by, e;
    if (b < 5120) {
        const int bb = b - 4096; e = bb >> 7; const int rem = bb & 127;
        bx = rem & 15; by = rem >> 4; R = 256; C = 512; in = W1; out = w1t;
    } else if (b < 7168) {
        const int bb = b - 5120; e = bb >> 8; const int rem = bb & 255;
        bx = rem & 15; by = rem >> 4; R = 512; C = 512; in = W2; out = w2t;
    } else {
        const int bb = b - 7168; e = bb >> 4; bx = 0; by = bb & 15;
        R = 512; C = 32; in = W3; out = w3t;
    }
    const int r0 = by * 32, c0 = bx * 32;
    const float* ine = in + (size_t)e * R * C;
    uint16_t* oute   = out + (size_t)e * R * C;
#pragma unroll
    for (int j = 0; j < 4; ++j)
        t[ty + 8 * j][tx] = ine[(size_t)(r0 + ty + 8 * j) * C + (c0 + tx)];
    __syncthreads();
#pragma unroll
    for (int j = 0; j < 4; ++j) {
        const int orow = c0 + ty + 8 * j;
        const int ocol = r0 + tx;
        oute[(size_t)orow * R + ocol] = f2bf(t[tx][ty + 8 * j]);
    }
}

// =====================================================================
// fused128: all 3 layers per block; block = 128 batch rows x one e.
// 8 waves. Grid (8e, 128) -> 1024 blocks = 4 rounds/CU (W re-stream
// HALVED vs r15's fused64). LDS 160KB:
//   [0,128K)  h1 [128][1024B] bf16 swz   (X pre-staged in [0,64K) as
//             4 subtiles [128][64k]@16KB — h1 epilogue only after ALL
//             of L1, when X is dead; L1 acc lives in 128 VGPRs)
//   [128K,160K) wstg: 2 x 16KB W dbuf (tile [128n][64k]) / h2q [128][256B]
// Engine, swizzle, MFMA maps: r12/r7/r15-verified, geometry only changed.
// L1/L2 swapped MFMA: D = mfma(W frag [n][k], act frag [m][k]) ->
//   col(lane&15)=batch row, row(kg*4+v)=out col.
// =====================================================================
__global__ __launch_bounds__(512, 1) void fused128(
    const uint16_t* __restrict__ xbf,
    const uint16_t* __restrict__ W1t, const float* __restrict__ b1,
    const uint16_t* __restrict__ W2t, const float* __restrict__ b2,
    const uint16_t* __restrict__ W3t, const float* __restrict__ b3,
    float* __restrict__ out)
{
    extern __shared__ char smem[];
    char* h1buf = smem;             // 128KB
    char* wstg  = smem + 131072;    // 32KB

    const int tid = threadIdx.x, wid = tid >> 6, lane = tid & 63;
    const int kg = lane >> 4, lr = lane & 15;
    const int e   = blockIdx.x;
    const int bm0 = blockIdx.y * 128;
    const int wm = wid >> 2, wn = wid & 3;        // L1/L2: 2m x 4n waves
    const int rlo = lane >> 3, pslot = lane & 7;
    const int lswz = (pslot ^ rlo) * 8;

    const uint16_t* Xb  = xbf + (size_t)bm0 * 256;
    const uint16_t* W1e = W1t + (size_t)e * 512 * 256;
    const uint16_t* W2e = W2t + (size_t)e * 512 * 512;
    const uint16_t* W3e = W3t + (size_t)e * 32 * 512;

    // stage W tile [128n][64k] (16KB) for n-quarter nq, k-tile kt
    auto stageW = [&](const uint16_t* We, int K, int cur, int nq, int kt) {
#pragma unroll
        for (int i = 0; i < 2; ++i) {
            const int r = wid * 16 + i * 8 + rlo;            // r&7 == rlo
            gload16(We + (size_t)(nq * 128 + r) * K + kt * 64 + lswz,
                    wstg + cur * 16384 + r * 128 + lane * 16);
        }
    };

    // ---- prologue: X [128][256] as 4 subtiles into h1buf[0:64K) ----
#pragma unroll
    for (int kt = 0; kt < 4; ++kt)
#pragma unroll
        for (int i = 0; i < 2; ++i) {
            const int r = wid * 16 + i * 8 + rlo;
            gload16(Xb + (size_t)r * 256 + kt * 64 + lswz,
                    h1buf + kt * 16384 + r * 128 + lane * 16);
        }
    stageW(W1e, 256, 0, 0, 0);
    __syncthreads();

    // ================= LAYER 1 (K=256): acc fully in registers =========
    f32x4 a1[4][4][2];               // [nq][bf][c] = 128 VGPR
#pragma unroll
    for (int q = 0; q < 4; ++q)
#pragma unroll
        for (int b = 0; b < 4; ++b)
#pragma unroll
            for (int c = 0; c < 2; ++c) a1[q][b][c] = f32x4{0.f, 0.f, 0.f, 0.f};

#pragma unroll
    for (int p = 0; p < 16; ++p) {   // p = nq*4 + kt
        const int nq = p >> 2, kt = p & 3, cur = p & 1;
        if (p + 1 < 16) stageW(W1e, 256, cur ^ 1, (p + 1) >> 2, (p + 1) & 3);
        asm volatile("" ::: "memory");
        __builtin_amdgcn_s_setprio(1);
#pragma unroll
        for (int kh = 0; kh < 2; ++kh) {
            bf16x8 wf[2], af[4];
#pragma unroll
            for (int c = 0; c < 2; ++c) {
                const int row = wn * 32 + c * 16 + lr;
                wf[c] = *(const bf16x8*)(wstg + cur * 16384 + row * 128 +
                                         (((kh * 4 + kg) ^ (row & 7)) << 4));
            }
#pragma unroll
            for (int b = 0; b < 4; ++b) {
                const int row = wm * 64 + b * 16 + lr;
                af[b] = *(const bf16x8*)(h1buf + kt * 16384 + row * 128 +
                                         (((kh * 4 + kg) ^ (row & 7)) << 4));
            }
#pragma unroll
            for (int b = 0; b < 4; ++b)
#pragma unroll
                for (int c = 0; c < 2; ++c)
                    a1[nq][b][c] = __builtin_amdgcn_mfma_f32_16x16x32_bf16(wf[c], af[b], a1[nq][b][c], 0, 0, 0);
        }
        __builtin_amdgcn_s_setprio(0);
        __syncthreads();
    }

    // ---- L1 epilogue (X dead): bias+relu -> h1 [128][1024B] swz ----
#pragma unroll
    for (int nq = 0; nq < 4; ++nq)
#pragma unroll
        for (int c = 0; c < 2; ++c) {
            const int col = nq * 128 + wn * 32 + c * 16 + kg * 4;
            const float4 bv = *(const float4*)(b1 + e * 512 + col);
#pragma unroll
            for (int b = 0; b < 4; ++b) {
                const float x0 = fmaxf(a1[nq][b][c][0] + bv.x, 0.f);
                const float x1 = fmaxf(a1[nq][b][c][1] + bv.y, 0.f);
                const float x2 = fmaxf(a1[nq][b][c][2] + bv.z, 0.f);
                const float x3 = fmaxf(a1[nq][b][c][3] + bv.w, 0.f);
                uint2 w;
                w.x = pk2bf(x0, x1);
                w.y = pk2bf(x2, x3);
                const int row = wm * 64 + b * 16 + lr;
                *(uint2*)(h1buf + row * 1024 + (((col << 1)) ^ ((row & 7) << 4))) = w;
            }
        }
    __syncthreads();

    // ========== LAYERS 2+3 per n-quarter (h2q -> wstg -> L3 partial) ====
    const int mf = wid >> 1, of = wid & 1;        // L3: 4m x 2o waves
    f32x4 o3[2];
    o3[0] = f32x4{0.f, 0.f, 0.f, 0.f};
    o3[1] = f32x4{0.f, 0.f, 0.f, 0.f};

#pragma unroll
    for (int nq = 0; nq < 4; ++nq) {
        stageW(W2e, 512, 0, nq, 0);
        __syncthreads();

        f32x4 a2[4][2];
#pragma unroll
        for (int b = 0; b < 4; ++b)
#pragma unroll
            for (int c = 0; c < 2; ++c) a2[b][c] = f32x4{0.f, 0.f, 0.f, 0.f};

#pragma unroll
        for (int kt = 0; kt < 8; ++kt) {
            const int cur = kt & 1;
            if (kt + 1 < 8) stageW(W2e, 512, cur ^ 1, nq, kt + 1);
            asm volatile("" ::: "memory");
            __builtin_amdgcn_s_setprio(1);
#pragma unroll
            for (int kh = 0; kh < 2; ++kh) {
                bf16x8 wf[2], af[4];
#pragma unroll
                for (int c = 0; c < 2; ++c) {
                    const int row = wn * 32 + c * 16 + lr;
                    wf[c] = *(const bf16x8*)(wstg + cur * 16384 + row * 128 +
                                             (((kh * 4 + kg) ^ (row & 7)) << 4));
                }
                const int kbyte = kt * 128 + kh * 64 + kg * 16;
#pragma unroll
                for (int b = 0; b < 4; ++b) {
                    const int row = wm * 64 + b * 16 + lr;
                    af[b] = *(const bf16x8*)(h1buf + row * 1024 +
                                             (kbyte ^ ((row & 7) << 4)));
                }
#pragma unroll
                for (int b = 0; b < 4; ++b)
#pragma unroll
                    for (int c = 0; c < 2; ++c)
                        a2[b][c] = __builtin_amdgcn_mfma_f32_16x16x32_bf16(wf[c], af[b], a2[b][c], 0, 0, 0);
            }
            __builtin_amdgcn_s_setprio(0);
            __syncthreads();
        }

        // epilogue: bias+relu -> h2q in wstg [128][256B] swz
#pragma unroll
        for (int c = 0; c < 2; ++c) {
            const int colh = wn * 32 + c * 16 + kg * 4;      // 0..127
            const float4 bv = *(const float4*)(b2 + e * 512 + nq * 128 + colh);
#pragma unroll
            for (int b = 0; b < 4; ++b) {
                const float x0 = fmaxf(a2[b][c][0] + bv.x, 0.f);
                const float x1 = fmaxf(a2[b][c][1] + bv.y, 0.f);
                const float x2 = fmaxf(a2[b][c][2] + bv.z, 0.f);
                const float x3 = fmaxf(a2[b][c][3] + bv.w, 0.f);
                uint2 w;
                w.x = pk2bf(x0, x1);
                w.y = pk2bf(x2, x3);
                const int row = wm * 64 + b * 16 + lr;
                *(uint2*)(wstg + row * 256 + (((colh << 1)) ^ ((row & 7) << 4))) = w;
            }
        }
        __syncthreads();

        // L3 partial: o3 += h2q @ W3[:, nq*128..+128)
        // swapped: D=mfma(W3 frag [o][k], h2 frag [m][k]) ->
        //   col(lane&15)=m-row, row(kg*4+v)=o-col  (r10/r15-verified)
#pragma unroll
        for (int kcq = 0; kcq < 4; ++kcq)
#pragma unroll
            for (int b2f = 0; b2f < 2; ++b2f) {
                const int row = mf * 32 + b2f * 16 + lr;
                const bf16x8 hb = *(const bf16x8*)(wstg + row * 256 +
                                                   ((kcq * 64 + kg * 16) ^ ((row & 7) << 4)));
                const bf16x8 w3 = *(const bf16x8*)(W3e + (size_t)(of * 16 + lr) * 512 +
                                                   nq * 128 + kcq * 32 + kg * 8);
                o3[b2f] = __builtin_amdgcn_mfma_f32_16x16x32_bf16(w3, hb, o3[b2f], 0, 0, 0);
            }
        __syncthreads();   // hb reads retired; wstg free for next nq
    }

    // ---- final store: bias3 + float4, row-contiguous ----
#pragma unroll
    for (int b2f = 0; b2f < 2; ++b2f) {
        const int col = e * 32 + of * 16 + kg * 4;
        const float4 bv = *(const float4*)(b3 + col);
        const int row = bm0 + mf * 32 + b2f * 16 + lr;
        float4 res;
        res.x = o3[b2f][0] + bv.x;
        res.y = o3[b2f][1] + bv.y;
        res.z = o3[b2f][2] + bv.z;
        res.w = o3[b2f][3] + bv.w;
        *(float4*)(out + (size_t)row * 256 + col) = res;
    }
}

// ---------------- host launch ----------------
extern "C" void kernel_launch(void* const* d_in, const int* in_sizes, int n_in,
                              void* d_out, int out_size, void* d_ws, size_t ws_size,
                              hipStream_t stream) {
    (void)in_sizes; (void)n_in; (void)out_size; (void)ws_size;
    const float* X  = (const float*)d_in[0];   // [16384,256]
    const float* W1 = (const float*)d_in[1];   // [8,256,512]
    const float* b1 = (const float*)d_in[2];   // [8,512]
    const float* W2 = (const float*)d_in[3];   // [8,512,512]
    const float* b2 = (const float*)d_in[4];   // [8,512]
    const float* W3 = (const float*)d_in[5];   // [8,512,32]
    const float* b3 = (const float*)d_in[6];   // [8,32]
    float* out = (float*)d_out;                // [16384,8,32]

    uint16_t* w1t = (uint16_t*)d_ws;           // [8][512][256] bf16  (2 MB)
    uint16_t* w2t = w1t + 8 * 256 * 512;       // [8][512][512] bf16  (4 MB)
    uint16_t* w3t = w2t + 8 * 512 * 512;       // [8][32][512]  bf16  (256 KB)
    uint16_t* xbf = w3t + 8 * 512 * 32;        // [16384][256]  bf16  (8 MB)

    prep<<<7296, 256, 0, stream>>>(X, W1, W2, W3, xbf, w1t, w2t, w3t);

    (void)hipFuncSetAttribute((const void*)fused128,
                              hipFuncAttributeMaxDynamicSharedMemorySize, 163840);
    fused128<<<dim3(8, 128), 512, 163840, stream>>>(xbf, w1t, b1, w2t, b2,
                                                    w3t, b3, out);
}